// Round 4
// baseline (692.002 us; speedup 1.0000x reference)
//
#include <hip/hip_runtime.h>
#include <hip/hip_bf16.h>
#include <math.h>

// Problem constants
#define DI   1024
#define EI   8
#define HI   4096
#define NI   4096   // B*T

typedef __bf16 bf16x8 __attribute__((ext_vector_type(8)));
typedef float  f32x4  __attribute__((ext_vector_type(4)));

// ---------- helpers ----------
__device__ __forceinline__ unsigned short f2bf(float f) {
  union { float f; unsigned u; } c; c.f = f;
  unsigned r = c.u + 0x7FFF + ((c.u >> 16) & 1);   // RNE
  return (unsigned short)(r >> 16);
}

// async global->LDS, 16B per lane; lds base must be wave-uniform
__device__ __forceinline__ void async16(const void* g, void* l) {
  __builtin_amdgcn_global_load_lds(
      (const __attribute__((address_space(1))) void*)g,
      (__attribute__((address_space(3))) void*)l, 16, 0, 0);
}

// exact-GELU via branch-free A&S 7.1.26 erf approx (|eps_erf| <= 1.5e-7).
__device__ __forceinline__ float gelu_fast(float v) {
  const float a = fabsf(v) * 0.70710678118f;                 // |x|/sqrt(2)
  const float t = __builtin_amdgcn_rcpf(fmaf(0.3275911f, a, 1.0f));
  float p = fmaf(1.061405429f, t, -1.453152027f);
  p = fmaf(p, t, 1.421413741f);
  p = fmaf(p, t, -0.284496736f);
  p = fmaf(p, t, 0.254829592f);
  p *= t;
  const float ex = __expf(-a * a);                           // e^{-a^2}
  float er = fmaf(-p, ex, 1.0f);                             // erf(a) in [0,1]
  er = copysignf(er, v);
  return 0.5f * v * (1.0f + er);
}

// ---------- kernel 1: fused LayerNorm + router (wave per token, NO atomics) ----------
__global__ __launch_bounds__(256) void ln_router_k(
    const float* __restrict__ x, const float* __restrict__ gamma,
    const float* __restrict__ beta, const float* __restrict__ gw,
    unsigned short* __restrict__ xnbf, float* __restrict__ probs_out,
    int* __restrict__ pairs, float2* __restrict__ gates2)
{
  const int t = threadIdx.x, lane = t & 63, wid = t >> 6;
  const int n = blockIdx.x * 4 + wid;

  const float4* xr = (const float4*)(x + (size_t)n * DI);
  float4 v[4];
  #pragma unroll
  for (int j = 0; j < 4; j++) v[j] = xr[lane * 4 + j];

  float s = 0.f, q = 0.f;
  #pragma unroll
  for (int j = 0; j < 4; j++) {
    s += v[j].x + v[j].y + v[j].z + v[j].w;
    q += v[j].x * v[j].x + v[j].y * v[j].y + v[j].z * v[j].z + v[j].w * v[j].w;
  }
  #pragma unroll
  for (int off = 1; off < 64; off <<= 1) {
    s += __shfl_xor(s, off);
    q += __shfl_xor(q, off);
  }
  const float mu = s * (1.0f / DI);
  const float rs = rsqrtf(q * (1.0f / DI) - mu * mu + 1e-5f);

  const float4* gr = (const float4*)gamma;
  const float4* br = (const float4*)beta;
  float xl[16];
  #pragma unroll
  for (int j = 0; j < 4; j++) {
    const float4 g4 = gr[lane * 4 + j];
    const float4 b4 = br[lane * 4 + j];
    xl[4 * j + 0] = (v[j].x - mu) * rs * g4.x + b4.x;
    xl[4 * j + 1] = (v[j].y - mu) * rs * g4.y + b4.y;
    xl[4 * j + 2] = (v[j].z - mu) * rs * g4.z + b4.z;
    xl[4 * j + 3] = (v[j].w - mu) * rs * g4.w + b4.w;
  }
  // store xn as bf16, 32 B per lane
  unsigned u[8];
  #pragma unroll
  for (int j = 0; j < 8; j++)
    u[j] = (unsigned)f2bf(xl[2 * j]) | ((unsigned)f2bf(xl[2 * j + 1]) << 16);
  uint4* dst = (uint4*)(xnbf + (size_t)n * DI + lane * 16);
  uint4 d0; d0.x = u[0]; d0.y = u[1]; d0.z = u[2]; d0.w = u[3];
  uint4 d1; d1.x = u[4]; d1.y = u[5]; d1.z = u[6]; d1.w = u[7];
  dst[0] = d0; dst[1] = d1;

  // router logits (fp32)
  float p[8];
  #pragma unroll
  for (int e = 0; e < 8; e++) p[e] = 0.f;
  #pragma unroll
  for (int j = 0; j < 16; j++) {
    const float4* grow = (const float4*)(gw + (size_t)(lane * 16 + j) * EI);
    const float4 ga = grow[0], gb = grow[1];
    const float xv = xl[j];
    p[0] += xv * ga.x; p[1] += xv * ga.y; p[2] += xv * ga.z; p[3] += xv * ga.w;
    p[4] += xv * gb.x; p[5] += xv * gb.y; p[6] += xv * gb.z; p[7] += xv * gb.w;
  }
  #pragma unroll
  for (int e = 0; e < 8; e++)
    #pragma unroll
    for (int off = 1; off < 64; off <<= 1) p[e] += __shfl_xor(p[e], off);

  if (lane == 0) {
    float pm = -1e30f;
    #pragma unroll
    for (int e = 0; e < 8; e++) pm = fmaxf(pm, p[e]);
    float pr[8], ps = 0.f;
    #pragma unroll
    for (int e = 0; e < 8; e++) { pr[e] = expf(p[e] - pm); ps += pr[e]; }
    const float inv = 1.0f / ps;
    #pragma unroll
    for (int e = 0; e < 8; e++) {
      pr[e] *= inv;
      probs_out[(size_t)n * EI + e] = pr[e];
    }
    // top-2, ties -> lowest index (matches lax.top_k)
    int i0 = 0; float m0 = pr[0];
    #pragma unroll
    for (int e = 1; e < 8; e++) if (pr[e] > m0) { m0 = pr[e]; i0 = e; }
    int i1 = -1; float m1 = -1e30f;
    #pragma unroll
    for (int e = 0; e < 8; e++) if (e != i0 && pr[e] > m1) { m1 = pr[e]; i1 = e; }
    const float ssum = m0 + m1 + 1e-8f;
    pairs[n] = i0 | (i1 << 8);
    float2 g2; g2.x = m0 / ssum; g2.y = m1 / ssum;
    gates2[n] = g2;
  }
}

// ---------- kernel 2: build compact per-expert lists + balance loss (1 block) ----------
__global__ __launch_bounds__(1024) void build_lists_k(
    const int* __restrict__ pairs, const float2* __restrict__ gates2,
    const float* __restrict__ probs, int* __restrict__ counts,
    int* __restrict__ offs, int* __restrict__ tok_list,
    float* __restrict__ gate_list, int2* __restrict__ ipos,
    float* __restrict__ out_bal)
{
  __shared__ int cnt[8];
  __shared__ int cur[8];
  __shared__ float wps[16][8];
  __shared__ float ps[8];
  const int t = threadIdx.x, lane = t & 63, wid = t >> 6;
  if (t < 8) cnt[t] = 0;
  __syncthreads();

  float acc[8];
  #pragma unroll
  for (int e = 0; e < 8; e++) acc[e] = 0.f;
  for (int n = t; n < NI; n += 1024) {
    const int pr = pairs[n];
    atomicAdd(&cnt[pr & 255], 1);
    atomicAdd(&cnt[pr >> 8], 1);
    const float4* prow = (const float4*)(probs + (size_t)n * EI);
    const float4 a = prow[0], b = prow[1];
    acc[0] += a.x; acc[1] += a.y; acc[2] += a.z; acc[3] += a.w;
    acc[4] += b.x; acc[5] += b.y; acc[6] += b.z; acc[7] += b.w;
  }
  #pragma unroll
  for (int e = 0; e < 8; e++)
    #pragma unroll
    for (int off = 1; off < 64; off <<= 1) acc[e] += __shfl_xor(acc[e], off);
  if (lane == 0)
    #pragma unroll
    for (int e = 0; e < 8; e++) wps[wid][e] = acc[e];
  __syncthreads();
  if (t < 8) {
    float sm = 0.f;
    for (int w = 0; w < 16; w++) sm += wps[w][t];
    ps[t] = sm;
  }
  __syncthreads();
  if (t == 0) {
    int off = 0; float bl = 0.f;
    for (int e = 0; e < 8; e++) {
      offs[e] = off; cur[e] = off; counts[e] = cnt[e];
      bl += (float)cnt[e] * ps[e];
      off += cnt[e];
    }
    *out_bal = 0.01f * 8.0f * bl / ((float)NI * (float)NI);
  }
  __syncthreads();
  for (int n = t; n < NI; n += 1024) {
    const int pr = pairs[n];
    const float2 g = gates2[n];
    const int p0 = atomicAdd(&cur[pr & 255], 1);
    tok_list[p0] = n; gate_list[p0] = g.x;
    const int p1 = atomicAdd(&cur[pr >> 8], 1);
    tok_list[p1] = n; gate_list[p1] = g.y;
    int2 ip; ip.x = p0; ip.y = p1;
    ipos[n] = ip;
  }
}

// ---------- kernel 3: transpose fp32 (R,C) -> bf16 (C,R), per expert in z ----------
__global__ __launch_bounds__(256) void transpose_cvt_k(
    const float* __restrict__ in, unsigned short* __restrict__ out, int R, int C)
{
  __shared__ float tile[64][65];
  const size_t eoff = (size_t)blockIdx.z * (size_t)R * (size_t)C;
  const int c0 = blockIdx.x * 64, r0 = blockIdx.y * 64;
  const int t = threadIdx.x;
  {
    const int col = (t & 15) * 4;
    #pragma unroll
    for (int ii = 0; ii < 4; ii++) {
      const int row = (t >> 4) + ii * 16;
      const float4 v = *(const float4*)(in + eoff + (size_t)(r0 + row) * C + c0 + col);
      tile[row][col + 0] = v.x; tile[row][col + 1] = v.y;
      tile[row][col + 2] = v.z; tile[row][col + 3] = v.w;
    }
  }
  __syncthreads();
  {
    const int grp = t & 7;
    #pragma unroll
    for (int jj = 0; jj < 2; jj++) {
      const int orow = (t >> 3) + jj * 32;
      unsigned short vs[8];
      #pragma unroll
      for (int u = 0; u < 8; u++) vs[u] = f2bf(tile[grp * 8 + u][orow]);
      uint4 pk;
      pk.x = (unsigned)vs[0] | ((unsigned)vs[1] << 16);
      pk.y = (unsigned)vs[2] | ((unsigned)vs[3] << 16);
      pk.z = (unsigned)vs[4] | ((unsigned)vs[5] << 16);
      pk.w = (unsigned)vs[6] | ((unsigned)vs[7] << 16);
      *(uint4*)(out + eoff + (size_t)(c0 + orow) * R + r0 + grp * 8) = pk;
    }
  }
}

// ---------- kernel 4: residual init out = x (atomic fallback path only) ----------
__global__ __launch_bounds__(256) void copy_x_k(const float* __restrict__ x, float* __restrict__ out)
{
  const size_t i = (size_t)blockIdx.x * 256 + threadIdx.x;
  ((float4*)out)[i] = ((const float4*)x)[i];
}

// ---------- kernel 5: grouped GEMM1 + bias + GELU -> h (bf16) ----------
// 256x256, BK=64 as 2 k-slices of 32, 8 waves (2Mx4N), 128 KiB LDS dbuf.
// 4-phase counted-vmcnt schedule: per phase stage ONE k-slice unit of tile t+1
// (2 loads/thread); vmcnt(6) at ph0 lands exactly tile-t ks0 (A0,B0), vmcnt(6)
// at ph2 lands ks1; never vmcnt(0) in the loop. 2 barriers/K-step; WAR-safe by
// ks0/ks1 region disjointness (laggards are at most one phase behind a barrier).
// Swizzle: phys col-group g holds logical g^((row>>1)&3) (R3-verified, 0 conflicts).
__global__ __launch_bounds__(512, 2) void ffn1_k(
    const unsigned short* __restrict__ xnbf, const unsigned short* __restrict__ w1t,
    const float* __restrict__ b1, unsigned short* __restrict__ hbuf,
    const int* __restrict__ tok_list, const int* __restrict__ counts,
    const int* __restrict__ offsets)
{
  const int e = blockIdx.z;
  const int cnt = counts[e];
  const int mt = blockIdx.y;
  if (mt * 256 >= cnt) return;
  const int n0 = blockIdx.x * 256;
  const int t = threadIdx.x, lane = t & 63, w = t >> 6;   // 8 waves
  const int wm = w & 1, wn = w >> 1;                      // 2M x 4N

  __shared__ __align__(16) unsigned short As[2][2][8192];  // [buf][kslice][256*32]
  __shared__ __align__(16) unsigned short Bs[2][2][8192];

  const int eoff = offsets[e];
  const unsigned short* srcA[2];
  const unsigned short* srcB[2];
  #pragma unroll
  for (int i = 0; i < 2; i++) {
    const int row = i * 128 + (t >> 2);                 // 0..255
    const int col = ((t & 3) ^ ((row >> 1) & 3)) * 8;   // pre-swizzled source col
    int idx = mt * 256 + row; if (idx > cnt - 1) idx = cnt - 1;  // clamp (dup unused)
    const int tok = tok_list[eoff + idx];
    srcA[i] = xnbf + (size_t)tok * DI + col;
    srcB[i] = w1t + (size_t)e * HI * DI + (size_t)(n0 + row) * DI + col;
  }
  const int db = (16 * w) * 32;   // wave-uniform LDS dest base (shorts); i=1 adds 4096

  f32x4 acc[8][4];
  const f32x4 zz = {0.f, 0.f, 0.f, 0.f};
  #pragma unroll
  for (int i = 0; i < 8; i++)
    #pragma unroll
    for (int j = 0; j < 4; j++) acc[i][j] = zz;

  const int mrow = wm * 128 + (lane & 15);
  const int nrow = wn * 64 + (lane & 15);
  const int ko = ((lane >> 4) ^ (((lane & 15) >> 1) & 3)) * 8;

  #define F1_STG_A(buf, ks, kofs) \
    { async16(srcA[0] + (kofs) + (ks) * 32, &As[buf][ks][db]); \
      async16(srcA[1] + (kofs) + (ks) * 32, &As[buf][ks][db + 4096]); }
  #define F1_STG_B(buf, ks, kofs) \
    { async16(srcB[0] + (kofs) + (ks) * 32, &Bs[buf][ks][db]); \
      async16(srcB[1] + (kofs) + (ks) * 32, &Bs[buf][ks][db + 4096]); }
  #define F1_LDA(buf, kk, mo) \
    { _Pragma("unroll") for (int mi = 0; mi < 4; mi++) \
        af[mi] = *(const bf16x8*)&As[buf][kk][(mrow + ((mo) + mi) * 16) * 32 + ko]; }
  #define F1_LDB(buf, kk) \
    { _Pragma("unroll") for (int ni = 0; ni < 4; ni++) \
        bfr[ni] = *(const bf16x8*)&Bs[buf][kk][(nrow + ni * 16) * 32 + ko]; }
  #define F1_MF(mo) \
    { __builtin_amdgcn_s_setprio(1); \
      _Pragma("unroll") for (int mi = 0; mi < 4; mi++) \
        _Pragma("unroll") for (int ni = 0; ni < 4; ni++) \
          acc[(mo) + mi][ni] = __builtin_amdgcn_mfma_f32_16x16x32_bf16( \
              af[mi], bfr[ni], acc[(mo) + mi][ni], 0, 0, 0); \
      __builtin_amdgcn_s_setprio(0); }

  // prologue: stage tile 0 (8 issues, no drain)
  F1_STG_A(0, 0, 0) F1_STG_B(0, 0, 0) F1_STG_A(0, 1, 0) F1_STG_B(0, 1, 0)

  bf16x8 af[4], bfr[4];
  const int NT = DI / 64;   // 16
  for (int ti = 0; ti < NT - 1; ++ti) {
    const int cur = ti & 1, nxt = cur ^ 1;
    const int k1 = (ti + 1) * 64;
    // ph0
    F1_STG_A(nxt, 0, k1)
    asm volatile("s_waitcnt vmcnt(6)" ::: "memory");
    __builtin_amdgcn_s_barrier();
    F1_LDA(cur, 0, 0) F1_LDB(cur, 0) F1_MF(0)
    // ph1
    F1_STG_B(nxt, 0, k1)
    F1_LDA(cur, 0, 4) F1_MF(4)
    // ph2
    F1_STG_A(nxt, 1, k1)
    asm volatile("s_waitcnt vmcnt(6)" ::: "memory");
    __builtin_amdgcn_s_barrier();
    F1_LDA(cur, 1, 0) F1_LDB(cur, 1) F1_MF(0)
    // ph3
    F1_STG_B(nxt, 1, k1)
    F1_LDA(cur, 1, 4) F1_MF(4)
  }
  { // last tile: no staging; counted then full drain (outside main loop)
    const int cur = (NT - 1) & 1;
    asm volatile("s_waitcnt vmcnt(4)" ::: "memory");
    __builtin_amdgcn_s_barrier();
    F1_LDA(cur, 0, 0) F1_LDB(cur, 0) F1_MF(0)
    F1_LDA(cur, 0, 4) F1_MF(4)
    asm volatile("s_waitcnt vmcnt(0)" ::: "memory");
    __builtin_amdgcn_s_barrier();
    F1_LDA(cur, 1, 0) F1_LDB(cur, 1) F1_MF(0)
    F1_LDA(cur, 1, 4) F1_MF(4)
  }
  #undef F1_STG_A
  #undef F1_STG_B
  #undef F1_LDA
  #undef F1_LDB
  #undef F1_MF

  // epilogue: bias + fast exact GELU, store bf16 h (guarded rows)
  const int hb = eoff + mt * 256;
  #pragma unroll
  for (int ni = 0; ni < 4; ni++) {
    const int col = n0 + wn * 64 + ni * 16 + (lane & 15);
    const float bias = b1[e * HI + col];
    #pragma unroll
    for (int mi = 0; mi < 8; mi++) {
      #pragma unroll
      for (int rg = 0; rg < 4; rg++) {
        const int rowl = wm * 128 + mi * 16 + ((lane >> 4) << 2) + rg;
        if (mt * 256 + rowl < cnt) {
          const float vv = gelu_fast(acc[mi][ni][rg] + bias);
          hbuf[(size_t)(hb + rowl) * HI + col] = f2bf(vv);
        }
      }
    }
  }
}

// ---------- kernel 6: grouped GEMM2 + bias -> eo ----------
// Same 4-phase counted-vmcnt schedule at 256x128 (BN=128 keeps >=256 live blocks
// at N=1024). 8 waves as 4M x 2N, acc[4][4], 96 KiB LDS. 6 loads/thread/step ->
// vmcnt(5) at ph0/ph2. B k-slice frags reused in regs across phase pairs.
__global__ __launch_bounds__(512, 2) void ffn2_k(
    const unsigned short* __restrict__ hbuf, const unsigned short* __restrict__ w2t,
    const float* __restrict__ b2, float* __restrict__ out,
    const int* __restrict__ tok_list, const float* __restrict__ gate_list,
    const int* __restrict__ counts, const int* __restrict__ offsets,
    float* __restrict__ eo)
{
  const int e = blockIdx.z;
  const int cnt = counts[e];
  const int mt = blockIdx.y;
  if (mt * 256 >= cnt) return;
  const int n0 = blockIdx.x * 128;
  const int t = threadIdx.x, lane = t & 63, w = t >> 6;
  const int wm = w & 3, wn = w >> 2;                      // 4M x 2N

  __shared__ __align__(16) unsigned short As2[2][2][8192]; // [buf][ks][256*32]
  __shared__ __align__(16) unsigned short Bs2[2][2][4096]; // [buf][ks][128*32]

  const int eoff = offsets[e];
  const int hb = eoff + mt * 256;
  const unsigned short* srcA[2];
  const unsigned short* srcB0;
  #pragma unroll
  for (int i = 0; i < 2; i++) {
    const int row = i * 128 + (t >> 2);
    const int col = ((t & 3) ^ ((row >> 1) & 3)) * 8;
    srcA[i] = hbuf + (size_t)(hb + row) * HI + col;       // h padded rows: in-ws garbage, guarded out
  }
  {
    const int row = t >> 2;                               // 0..127
    const int col = ((t & 3) ^ ((row >> 1) & 3)) * 8;
    srcB0 = w2t + (size_t)e * DI * HI + (size_t)(n0 + row) * HI + col;
  }
  const int db = (16 * w) * 32;

  f32x4 acc[4][4];
  const f32x4 zz = {0.f, 0.f, 0.f, 0.f};
  #pragma unroll
  for (int i = 0; i < 4; i++)
    #pragma unroll
    for (int j = 0; j < 4; j++) acc[i][j] = zz;

  const int mrow = wm * 64 + (lane & 15);
  const int nrow = wn * 64 + (lane & 15);
  const int ko = ((lane >> 4) ^ (((lane & 15) >> 1) & 3)) * 8;

  #define F2_STG_A(buf, ks, kofs) \
    { async16(srcA[0] + (kofs) + (ks) * 32, &As2[buf][ks][db]); \
      async16(srcA[1] + (kofs) + (ks) * 32, &As2[buf][ks][db + 4096]); }
  #define F2_STG_B(buf, ks, kofs) \
    { async16(srcB0 + (kofs) + (ks) * 32, &Bs2[buf][ks][db]); }
  #define F2_LDA(buf, kk) \
    { _Pragma("unroll") for (int mi = 0; mi < 4; mi++) \
        af[mi] = *(const bf16x8*)&As2[buf][kk][(mrow + mi * 16) * 32 + ko]; }
  #define F2_LDB(buf, kk, no) \
    { _Pragma("unroll") for (int ni = 0; ni < 2; ni++) \
        bfr[ni] = *(const bf16x8*)&Bs2[buf][kk][(nrow + ((no) + ni) * 16) * 32 + ko]; }
  #define F2_MF(no) \
    { __builtin_amdgcn_s_setprio(1); \
      _Pragma("unroll") for (int mi = 0; mi < 4; mi++) \
        _Pragma("unroll") for (int ni = 0; ni < 2; ni++) \
          acc[mi][(no) + ni] = __builtin_amdgcn_mfma_f32_16x16x32_bf16( \
              af[mi], bfr[ni], acc[mi][(no) + ni], 0, 0, 0); \
      __builtin_amdgcn_s_setprio(0); }

  // prologue: stage tile 0 (6 issues)
  F2_STG_A(0, 0, 0) F2_STG_B(0, 0, 0) F2_STG_A(0, 1, 0) F2_STG_B(0, 1, 0)

  bf16x8 af[4], bfr[2];
  const int NT = HI / 64;   // 64
  for (int ti = 0; ti < NT - 1; ++ti) {
    const int cur = ti & 1, nxt = cur ^ 1;
    const int k1 = (ti + 1) * 64;
    // ph0
    F2_STG_A(nxt, 0, k1)
    asm volatile("s_waitcnt vmcnt(5)" ::: "memory");
    __builtin_amdgcn_s_barrier();
    F2_LDA(cur, 0) F2_LDB(cur, 0, 0) F2_MF(0)
    // ph1
    F2_STG_B(nxt, 0, k1)
    F2_LDB(cur, 0, 2) F2_MF(2)
    // ph2
    F2_STG_A(nxt, 1, k1)
    asm volatile("s_waitcnt vmcnt(5)" ::: "memory");
    __builtin_amdgcn_s_barrier();
    F2_LDA(cur, 1) F2_LDB(cur, 1, 0) F2_MF(0)
    // ph3
    F2_STG_B(nxt, 1, k1)
    F2_LDB(cur, 1, 2) F2_MF(2)
  }
  { // last tile
    const int cur = (NT - 1) & 1;
    asm volatile("s_waitcnt vmcnt(3)" ::: "memory");
    __builtin_amdgcn_s_barrier();
    F2_LDA(cur, 0) F2_LDB(cur, 0, 0) F2_MF(0)
    F2_LDB(cur, 0, 2) F2_MF(2)
    asm volatile("s_waitcnt vmcnt(0)" ::: "memory");
    __builtin_amdgcn_s_barrier();
    F2_LDA(cur, 1) F2_LDB(cur, 1, 0) F2_MF(0)
    F2_LDB(cur, 1, 2) F2_MF(2)
  }
  #undef F2_STG_A
  #undef F2_STG_B
  #undef F2_LDA
  #undef F2_LDB
  #undef F2_MF

  float bias[4];
  #pragma unroll
  for (int ni = 0; ni < 4; ni++)
    bias[ni] = b2[e * DI + n0 + wn * 64 + ni * 16 + (lane & 15)];

  if (eo) {
    #pragma unroll
    for (int mi = 0; mi < 4; mi++) {
      #pragma unroll
      for (int rg = 0; rg < 4; rg++) {
        const int rowl = wm * 64 + mi * 16 + ((lane >> 4) << 2) + rg;
        const int gidx = mt * 256 + rowl;
        if (gidx < cnt) {
          float* erow = eo + (size_t)(hb + rowl) * DI;
          #pragma unroll
          for (int ni = 0; ni < 4; ni++) {
            const int col = n0 + wn * 64 + ni * 16 + (lane & 15);
            erow[col] = acc[mi][ni][rg] + bias[ni];
          }
        }
      }
    }
  } else {
    #pragma unroll
    for (int mi = 0; mi < 4; mi++) {
      #pragma unroll
      for (int rg = 0; rg < 4; rg++) {
        const int rowl = wm * 64 + mi * 16 + ((lane >> 4) << 2) + rg;
        const int gidx = mt * 256 + rowl;
        if (gidx < cnt) {
          const int tok = tok_list[eoff + gidx];
          const float gte = gate_list[eoff + gidx];
          float* orow = out + (size_t)tok * DI;
          #pragma unroll
          for (int ni = 0; ni < 4; ni++) {
            const int col = n0 + wn * 64 + ni * 16 + (lane & 15);
            atomicAdd(orow + col, (acc[mi][ni][rg] + bias[ni]) * gte);
          }
        }
      }
    }
  }
}

// ---------- kernel 7: out = x + g0*eo[p0] + g1*eo[p1] ----------
__global__ __launch_bounds__(256) void combine_k(
    const float* __restrict__ x, const float* __restrict__ eo,
    const int2* __restrict__ ipos, const float2* __restrict__ gates2,
    float* __restrict__ out)
{
  const int n = blockIdx.x, t = threadIdx.x;
  const int2 pp = ipos[n];
  const float2 gg = gates2[n];
  const float4 a = ((const float4*)(x  + (size_t)n    * DI))[t];
  const float4 b = ((const float4*)(eo + (size_t)pp.x * DI))[t];
  const float4 c = ((const float4*)(eo + (size_t)pp.y * DI))[t];
  float4 r;
  r.x = a.x + gg.x * b.x + gg.y * c.x;
  r.y = a.y + gg.x * b.y + gg.y * c.y;
  r.z = a.z + gg.x * b.z + gg.y * c.z;
  r.w = a.w + gg.x * b.w + gg.y * c.w;
  ((float4*)(out + (size_t)n * DI))[t] = r;
}

// ---------- launch ----------
extern "C" void kernel_launch(void* const* d_in, const int* in_sizes, int n_in,
                              void* d_out, int out_size, void* d_ws, size_t ws_size,
                              hipStream_t stream)
{
  const float* x   = (const float*)d_in[0];
  const float* gam = (const float*)d_in[1];
  const float* bet = (const float*)d_in[2];
  const float* gw  = (const float*)d_in[3];
  const float* w1  = (const float*)d_in[4];
  const float* b1  = (const float*)d_in[5];
  const float* w2  = (const float*)d_in[6];
  const float* b2  = (const float*)d_in[7];
  float* out = (float*)d_out;

  char* ws = (char*)d_ws;
  int*    counts = (int*)(ws + 0);
  int*    offs   = (int*)(ws + 64);
  int*    pairs  = (int*)(ws + 1024);
  float2* gates2 = (float2*)(ws + 20480);
  int*    tok    = (int*)(ws + 57344);
  float*  gate   = (float*)(ws + 90112);
  int2*   ipos   = (int2*)(ws + 122880);
  unsigned short* xnbf = (unsigned short*)(ws + 262656);
  unsigned short* wt   = (unsigned short*)(ws + 8651264);
  unsigned short* hbuf = (unsigned short*)(ws + 75760128);
  const bool use_eo = (ws_size >= 177472000ull);
  float* eo = use_eo ? (float*)(ws + 143917568) : (float*)nullptr;

  float* bal_out   = out + (size_t)NI * DI;
  float* probs_out = bal_out + 1;

  ln_router_k<<<NI / 4, 256, 0, stream>>>(x, gam, bet, gw, xnbf, probs_out, pairs, gates2);
  build_lists_k<<<1, 1024, 0, stream>>>(pairs, gates2, probs_out, counts, offs, tok, gate, ipos, bal_out);
  transpose_cvt_k<<<dim3(HI / 64, DI / 64, EI), 256, 0, stream>>>(w1, wt, DI, HI);
  if (!use_eo)
    copy_x_k<<<(NI * DI / 4) / 256, 256, 0, stream>>>(x, out);
  ffn1_k<<<dim3(HI / 256, 16, EI), 512, 0, stream>>>(xnbf, wt, b1, hbuf, tok, counts, offs);
  transpose_cvt_k<<<dim3(DI / 64, HI / 64, EI), 256, 0, stream>>>(w2, wt, HI, DI);
  ffn2_k<<<dim3(DI / 128, 16, EI), 512, 0, stream>>>(hbuf, wt, b2, out, tok, gate, counts, offs, eo);
  if (use_eo)
    combine_k<<<NI, 256, 0, stream>>>(x, eo, ipos, gates2, out);
}

// Round 5
// 690.184 us; speedup vs baseline: 1.0026x; 1.0026x over previous
//
#include <hip/hip_runtime.h>
#include <hip/hip_bf16.h>
#include <math.h>

// Problem constants
#define DI   1024
#define EI   8
#define HI   4096
#define NI   4096   // B*T

typedef __bf16 bf16x8 __attribute__((ext_vector_type(8)));
typedef float  f32x4  __attribute__((ext_vector_type(4)));

// ---------- helpers ----------
__device__ __forceinline__ unsigned short f2bf(float f) {
  union { float f; unsigned u; } c; c.f = f;
  unsigned r = c.u + 0x7FFF + ((c.u >> 16) & 1);   // RNE
  return (unsigned short)(r >> 16);
}

// async global->LDS, 16B per lane; lds base must be wave-uniform
__device__ __forceinline__ void async16(const void* g, void* l) {
  __builtin_amdgcn_global_load_lds(
      (const __attribute__((address_space(1))) void*)g,
      (__attribute__((address_space(3))) void*)l, 16, 0, 0);
}

// exact-GELU via branch-free A&S 7.1.26 erf approx (|eps_erf| <= 1.5e-7).
__device__ __forceinline__ float gelu_fast(float v) {
  const float a = fabsf(v) * 0.70710678118f;                 // |x|/sqrt(2)
  const float t = __builtin_amdgcn_rcpf(fmaf(0.3275911f, a, 1.0f));
  float p = fmaf(1.061405429f, t, -1.453152027f);
  p = fmaf(p, t, 1.421413741f);
  p = fmaf(p, t, -0.284496736f);
  p = fmaf(p, t, 0.254829592f);
  p *= t;
  const float ex = __expf(-a * a);                           // e^{-a^2}
  float er = fmaf(-p, ex, 1.0f);                             // erf(a) in [0,1]
  er = copysignf(er, v);
  return 0.5f * v * (1.0f + er);
}

// ---------- kernel 1: fused LayerNorm + router (wave per token, NO atomics) ----------
__global__ __launch_bounds__(256) void ln_router_k(
    const float* __restrict__ x, const float* __restrict__ gamma,
    const float* __restrict__ beta, const float* __restrict__ gw,
    unsigned short* __restrict__ xnbf, float* __restrict__ probs_out,
    int* __restrict__ pairs, float2* __restrict__ gates2)
{
  const int t = threadIdx.x, lane = t & 63, wid = t >> 6;
  const int n = blockIdx.x * 4 + wid;

  const float4* xr = (const float4*)(x + (size_t)n * DI);
  float4 v[4];
  #pragma unroll
  for (int j = 0; j < 4; j++) v[j] = xr[lane * 4 + j];

  float s = 0.f, q = 0.f;
  #pragma unroll
  for (int j = 0; j < 4; j++) {
    s += v[j].x + v[j].y + v[j].z + v[j].w;
    q += v[j].x * v[j].x + v[j].y * v[j].y + v[j].z * v[j].z + v[j].w * v[j].w;
  }
  #pragma unroll
  for (int off = 1; off < 64; off <<= 1) {
    s += __shfl_xor(s, off);
    q += __shfl_xor(q, off);
  }
  const float mu = s * (1.0f / DI);
  const float rs = rsqrtf(q * (1.0f / DI) - mu * mu + 1e-5f);

  const float4* gr = (const float4*)gamma;
  const float4* br = (const float4*)beta;
  float xl[16];
  #pragma unroll
  for (int j = 0; j < 4; j++) {
    const float4 g4 = gr[lane * 4 + j];
    const float4 b4 = br[lane * 4 + j];
    xl[4 * j + 0] = (v[j].x - mu) * rs * g4.x + b4.x;
    xl[4 * j + 1] = (v[j].y - mu) * rs * g4.y + b4.y;
    xl[4 * j + 2] = (v[j].z - mu) * rs * g4.z + b4.z;
    xl[4 * j + 3] = (v[j].w - mu) * rs * g4.w + b4.w;
  }
  // store xn as bf16, 32 B per lane
  unsigned u[8];
  #pragma unroll
  for (int j = 0; j < 8; j++)
    u[j] = (unsigned)f2bf(xl[2 * j]) | ((unsigned)f2bf(xl[2 * j + 1]) << 16);
  uint4* dst = (uint4*)(xnbf + (size_t)n * DI + lane * 16);
  uint4 d0; d0.x = u[0]; d0.y = u[1]; d0.z = u[2]; d0.w = u[3];
  uint4 d1; d1.x = u[4]; d1.y = u[5]; d1.z = u[6]; d1.w = u[7];
  dst[0] = d0; dst[1] = d1;

  // router logits (fp32)
  float p[8];
  #pragma unroll
  for (int e = 0; e < 8; e++) p[e] = 0.f;
  #pragma unroll
  for (int j = 0; j < 16; j++) {
    const float4* grow = (const float4*)(gw + (size_t)(lane * 16 + j) * EI);
    const float4 ga = grow[0], gb = grow[1];
    const float xv = xl[j];
    p[0] += xv * ga.x; p[1] += xv * ga.y; p[2] += xv * ga.z; p[3] += xv * ga.w;
    p[4] += xv * gb.x; p[5] += xv * gb.y; p[6] += xv * gb.z; p[7] += xv * gb.w;
  }
  #pragma unroll
  for (int e = 0; e < 8; e++)
    #pragma unroll
    for (int off = 1; off < 64; off <<= 1) p[e] += __shfl_xor(p[e], off);

  if (lane == 0) {
    float pm = -1e30f;
    #pragma unroll
    for (int e = 0; e < 8; e++) pm = fmaxf(pm, p[e]);
    float pr[8], ps = 0.f;
    #pragma unroll
    for (int e = 0; e < 8; e++) { pr[e] = expf(p[e] - pm); ps += pr[e]; }
    const float inv = 1.0f / ps;
    #pragma unroll
    for (int e = 0; e < 8; e++) {
      pr[e] *= inv;
      probs_out[(size_t)n * EI + e] = pr[e];
    }
    // top-2, ties -> lowest index (matches lax.top_k)
    int i0 = 0; float m0 = pr[0];
    #pragma unroll
    for (int e = 1; e < 8; e++) if (pr[e] > m0) { m0 = pr[e]; i0 = e; }
    int i1 = -1; float m1 = -1e30f;
    #pragma unroll
    for (int e = 0; e < 8; e++) if (e != i0 && pr[e] > m1) { m1 = pr[e]; i1 = e; }
    const float ssum = m0 + m1 + 1e-8f;
    pairs[n] = i0 | (i1 << 8);
    float2 g2; g2.x = m0 / ssum; g2.y = m1 / ssum;
    gates2[n] = g2;
  }
}

// ---------- kernel 2: build compact per-expert lists + balance loss (1 block) ----------
__global__ __launch_bounds__(1024) void build_lists_k(
    const int* __restrict__ pairs, const float2* __restrict__ gates2,
    const float* __restrict__ probs, int* __restrict__ counts,
    int* __restrict__ offs, int* __restrict__ tok_list,
    float* __restrict__ gate_list, int2* __restrict__ ipos,
    float* __restrict__ out_bal)
{
  __shared__ int cnt[8];
  __shared__ int cur[8];
  __shared__ float wps[16][8];
  __shared__ float ps[8];
  const int t = threadIdx.x, lane = t & 63, wid = t >> 6;
  if (t < 8) cnt[t] = 0;
  __syncthreads();

  float acc[8];
  #pragma unroll
  for (int e = 0; e < 8; e++) acc[e] = 0.f;
  for (int n = t; n < NI; n += 1024) {
    const int pr = pairs[n];
    atomicAdd(&cnt[pr & 255], 1);
    atomicAdd(&cnt[pr >> 8], 1);
    const float4* prow = (const float4*)(probs + (size_t)n * EI);
    const float4 a = prow[0], b = prow[1];
    acc[0] += a.x; acc[1] += a.y; acc[2] += a.z; acc[3] += a.w;
    acc[4] += b.x; acc[5] += b.y; acc[6] += b.z; acc[7] += b.w;
  }
  #pragma unroll
  for (int e = 0; e < 8; e++)
    #pragma unroll
    for (int off = 1; off < 64; off <<= 1) acc[e] += __shfl_xor(acc[e], off);
  if (lane == 0)
    #pragma unroll
    for (int e = 0; e < 8; e++) wps[wid][e] = acc[e];
  __syncthreads();
  if (t < 8) {
    float sm = 0.f;
    for (int w = 0; w < 16; w++) sm += wps[w][t];
    ps[t] = sm;
  }
  __syncthreads();
  if (t == 0) {
    int off = 0; float bl = 0.f;
    for (int e = 0; e < 8; e++) {
      offs[e] = off; cur[e] = off; counts[e] = cnt[e];
      bl += (float)cnt[e] * ps[e];
      off += cnt[e];
    }
    *out_bal = 0.01f * 8.0f * bl / ((float)NI * (float)NI);
  }
  __syncthreads();
  for (int n = t; n < NI; n += 1024) {
    const int pr = pairs[n];
    const float2 g = gates2[n];
    const int p0 = atomicAdd(&cur[pr & 255], 1);
    tok_list[p0] = n; gate_list[p0] = g.x;
    const int p1 = atomicAdd(&cur[pr >> 8], 1);
    tok_list[p1] = n; gate_list[p1] = g.y;
    int2 ip; ip.x = p0; ip.y = p1;
    ipos[n] = ip;
  }
}

// ---------- kernel 3: transpose fp32 (R,C) -> bf16 (C,R), per expert in z ----------
__global__ __launch_bounds__(256) void transpose_cvt_k(
    const float* __restrict__ in, unsigned short* __restrict__ out, int R, int C)
{
  __shared__ float tile[64][65];
  const size_t eoff = (size_t)blockIdx.z * (size_t)R * (size_t)C;
  const int c0 = blockIdx.x * 64, r0 = blockIdx.y * 64;
  const int t = threadIdx.x;
  {
    const int col = (t & 15) * 4;
    #pragma unroll
    for (int ii = 0; ii < 4; ii++) {
      const int row = (t >> 4) + ii * 16;
      const float4 v = *(const float4*)(in + eoff + (size_t)(r0 + row) * C + c0 + col);
      tile[row][col + 0] = v.x; tile[row][col + 1] = v.y;
      tile[row][col + 2] = v.z; tile[row][col + 3] = v.w;
    }
  }
  __syncthreads();
  {
    const int grp = t & 7;
    #pragma unroll
    for (int jj = 0; jj < 2; jj++) {
      const int orow = (t >> 3) + jj * 32;
      unsigned short vs[8];
      #pragma unroll
      for (int u = 0; u < 8; u++) vs[u] = f2bf(tile[grp * 8 + u][orow]);
      uint4 pk;
      pk.x = (unsigned)vs[0] | ((unsigned)vs[1] << 16);
      pk.y = (unsigned)vs[2] | ((unsigned)vs[3] << 16);
      pk.z = (unsigned)vs[4] | ((unsigned)vs[5] << 16);
      pk.w = (unsigned)vs[6] | ((unsigned)vs[7] << 16);
      *(uint4*)(out + eoff + (size_t)(c0 + orow) * R + r0 + grp * 8) = pk;
    }
  }
}

// ---------- kernel 4: residual init out = x (atomic fallback path only) ----------
__global__ __launch_bounds__(256) void copy_x_k(const float* __restrict__ x, float* __restrict__ out)
{
  const size_t i = (size_t)blockIdx.x * 256 + threadIdx.x;
  ((float4*)out)[i] = ((const float4*)x)[i];
}

// ---------- kernel 5: grouped GEMM1 + bias + GELU -> h (bf16) ----------
// T3-minimum template (m230-V0 structure, 682 TF @ this shape): 256x256 tile,
// BK=64, 8 waves (2Mx4N), 128 KiB LDS dbuf. Per K-step: STAGE(next) first,
// ds_read+MFMA(cur) [compiler lgkmcnt], setprio around MFMA, then ONE
// vmcnt(0)+s_barrier. Next tile's loads land during compute; drain is cheap.
__global__ __launch_bounds__(512, 2) void ffn1_k(
    const unsigned short* __restrict__ xnbf, const unsigned short* __restrict__ w1t,
    const float* __restrict__ b1, unsigned short* __restrict__ hbuf,
    const int* __restrict__ tok_list, const int* __restrict__ counts,
    const int* __restrict__ offsets)
{
  const int e = blockIdx.z;
  const int cnt = counts[e];
  const int mt = blockIdx.y;
  if (mt * 256 >= cnt) return;
  const int n0 = blockIdx.x * 256;
  const int t = threadIdx.x, lane = t & 63, w = t >> 6;   // 8 waves
  const int wm = w & 1, wn = w >> 1;                      // 2M x 4N

  __shared__ __align__(16) unsigned short As[2][256 * 64];  // 32 KB each buf
  __shared__ __align__(16) unsigned short Bs[2][256 * 64];

  const int sub = lane >> 3;                  // row within 8-row stripe
  const int kc  = (((lane & 7) ^ sub) * 8);   // pre-swizzled source col-group (R0-proven)
  const int eoff = offsets[e];
  const unsigned short* baseA[4];
  const unsigned short* baseB[4];
  #pragma unroll
  for (int r = 0; r < 4; r++) {
    const int row = (w << 5) + r * 8 + sub;   // 0..255
    int idx = mt * 256 + row; if (idx > cnt - 1) idx = cnt - 1;  // clamp (dup unused)
    const int tok = tok_list[eoff + idx];
    baseA[r] = xnbf + (size_t)tok * DI + kc;
    baseB[r] = w1t + (size_t)e * HI * DI + (size_t)(n0 + row) * DI + kc;
  }

  f32x4 acc[8][4];
  const f32x4 zz = {0.f, 0.f, 0.f, 0.f};
  #pragma unroll
  for (int i = 0; i < 8; i++)
    #pragma unroll
    for (int j = 0; j < 4; j++) acc[i][j] = zz;

  const int mrow = wm * 128 + (lane & 15);
  const int nrow = wn * 64 + (lane & 15);
  const int ksw[2] = { (((lane >> 4) ^ (lane & 7)) * 8),
                       ((((lane >> 4) + 4) ^ (lane & 7)) * 8) };

  #define F1_STAGE(buf, k0s)                                          \
    { _Pragma("unroll")                                               \
      for (int r = 0; r < 4; r++) {                                   \
        async16(baseA[r] + (k0s), &As[buf][((w << 5) + r * 8) * 64]); \
        async16(baseB[r] + (k0s), &Bs[buf][((w << 5) + r * 8) * 64]); \
      } }

  #define F1_COMPUTE(buf)                                                     \
    { _Pragma("unroll")                                                       \
      for (int kk = 0; kk < 2; kk++) {                                        \
        const int ko = ksw[kk];                                               \
        bf16x8 af[8], bfr[4];                                                 \
        _Pragma("unroll")                                                     \
        for (int ni = 0; ni < 4; ni++)                                        \
          bfr[ni] = *(const bf16x8*)&Bs[buf][(nrow + ni * 16) * 64 + ko];     \
        _Pragma("unroll")                                                     \
        for (int mi = 0; mi < 8; mi++)                                        \
          af[mi] = *(const bf16x8*)&As[buf][(mrow + mi * 16) * 64 + ko];      \
        __builtin_amdgcn_s_setprio(1);                                        \
        _Pragma("unroll")                                                     \
        for (int mi = 0; mi < 8; mi++)                                        \
          _Pragma("unroll")                                                   \
          for (int ni = 0; ni < 4; ni++)                                      \
            acc[mi][ni] = __builtin_amdgcn_mfma_f32_16x16x32_bf16(            \
                af[mi], bfr[ni], acc[mi][ni], 0, 0, 0);                       \
        __builtin_amdgcn_s_setprio(0);                                        \
      } }

  // prologue: stage tile 0 -> buf 0; drain; barrier
  F1_STAGE(0, 0)
  asm volatile("s_waitcnt vmcnt(0)" ::: "memory");
  __builtin_amdgcn_s_barrier();

  const int NT = DI / 64;   // 16
  int cur = 0;
  for (int ti = 0; ti < NT - 1; ++ti) {
    F1_STAGE(cur ^ 1, (ti + 1) * 64)   // issue next-tile loads FIRST
    F1_COMPUTE(cur)                    // ds_read+MFMA current (compiler lgkmcnt)
    asm volatile("s_waitcnt vmcnt(0)" ::: "memory");  // next tile landed (covered by compute)
    __builtin_amdgcn_s_barrier();
    cur ^= 1;
  }
  F1_COMPUTE(cur)                      // last tile, no prefetch

  #undef F1_STAGE
  #undef F1_COMPUTE

  // epilogue: bias + fast exact GELU, store bf16 h (guarded rows)
  const int hb = eoff + mt * 256;
  #pragma unroll
  for (int ni = 0; ni < 4; ni++) {
    const int col = n0 + wn * 64 + ni * 16 + (lane & 15);
    const float bias = b1[e * HI + col];
    #pragma unroll
    for (int mi = 0; mi < 8; mi++) {
      #pragma unroll
      for (int rg = 0; rg < 4; rg++) {
        const int rowl = wm * 128 + mi * 16 + ((lane >> 4) << 2) + rg;
        if (mt * 256 + rowl < cnt) {
          const float vv = gelu_fast(acc[mi][ni][rg] + bias);
          hbuf[(size_t)(hb + rowl) * HI + col] = f2bf(vv);
        }
      }
    }
  }
}

// ---------- kernel 6: grouped GEMM2 + bias -> eo ----------
// Same T3-minimum template at 256x128 (BN=128 keeps 256 live blocks at N=1024).
// 8 waves as 4M x 2N, acc[4][4], 96 KiB LDS dbuf.
__global__ __launch_bounds__(512, 2) void ffn2_k(
    const unsigned short* __restrict__ hbuf, const unsigned short* __restrict__ w2t,
    const float* __restrict__ b2, float* __restrict__ out,
    const int* __restrict__ tok_list, const float* __restrict__ gate_list,
    const int* __restrict__ counts, const int* __restrict__ offsets,
    float* __restrict__ eo)
{
  const int e = blockIdx.z;
  const int cnt = counts[e];
  const int mt = blockIdx.y;
  if (mt * 256 >= cnt) return;
  const int n0 = blockIdx.x * 128;
  const int t = threadIdx.x, lane = t & 63, w = t >> 6;
  const int wm = w & 3, wn = w >> 2;                      // 4M x 2N

  __shared__ __align__(16) unsigned short As2[2][256 * 64]; // 32 KB each buf
  __shared__ __align__(16) unsigned short Bs2[2][128 * 64]; // 16 KB each buf

  const int sub = lane >> 3;
  const int kc = (((lane & 7) ^ sub) * 8);
  const int eoff = offsets[e];
  const int hb = eoff + mt * 256;
  const unsigned short* baseA[4];
  const unsigned short* baseB[2];
  #pragma unroll
  for (int r = 0; r < 4; r++) {
    const int row = (w << 5) + r * 8 + sub;               // 0..255
    int idx = mt * 256 + row; if (idx > cnt - 1) idx = cnt - 1;  // clamp into list range
    baseA[r] = hbuf + (size_t)(eoff + idx) * HI + kc;
  }
  #pragma unroll
  for (int is = 0; is < 2; is++) {
    const int row = (w << 4) + is * 8 + sub;              // 0..127
    baseB[is] = w2t + (size_t)e * DI * HI + (size_t)(n0 + row) * HI + kc;
  }

  f32x4 acc[4][4];
  const f32x4 zz = {0.f, 0.f, 0.f, 0.f};
  #pragma unroll
  for (int i = 0; i < 4; i++)
    #pragma unroll
    for (int j = 0; j < 4; j++) acc[i][j] = zz;

  const int mrow = wm * 64 + (lane & 15);
  const int nrow = wn * 64 + (lane & 15);
  const int ksw[2] = { (((lane >> 4) ^ (lane & 7)) * 8),
                       ((((lane >> 4) + 4) ^ (lane & 7)) * 8) };

  #define F2_STAGE(buf, k0s)                                             \
    { _Pragma("unroll")                                                  \
      for (int r = 0; r < 4; r++)                                        \
        async16(baseA[r] + (k0s), &As2[buf][((w << 5) + r * 8) * 64]);   \
      _Pragma("unroll")                                                  \
      for (int is = 0; is < 2; is++)                                     \
        async16(baseB[is] + (k0s), &Bs2[buf][((w << 4) + is * 8) * 64]); \
    }

  #define F2_COMPUTE(buf)                                                     \
    { _Pragma("unroll")                                                       \
      for (int kk = 0; kk < 2; kk++) {                                        \
        const int ko = ksw[kk];                                               \
        bf16x8 af[4], bfr[4];                                                 \
        _Pragma("unroll")                                                     \
        for (int ni = 0; ni < 4; ni++)                                        \
          bfr[ni] = *(const bf16x8*)&Bs2[buf][(nrow + ni * 16) * 64 + ko];    \
        _Pragma("unroll")                                                     \
        for (int mi = 0; mi < 4; mi++)                                        \
          af[mi] = *(const bf16x8*)&As2[buf][(mrow + mi * 16) * 64 + ko];     \
        __builtin_amdgcn_s_setprio(1);                                        \
        _Pragma("unroll")                                                     \
        for (int mi = 0; mi < 4; mi++)                                        \
          _Pragma("unroll")                                                   \
          for (int ni = 0; ni < 4; ni++)                                      \
            acc[mi][ni] = __builtin_amdgcn_mfma_f32_16x16x32_bf16(            \
                af[mi], bfr[ni], acc[mi][ni], 0, 0, 0);                       \
        __builtin_amdgcn_s_setprio(0);                                        \
      } }

  // prologue
  F2_STAGE(0, 0)
  asm volatile("s_waitcnt vmcnt(0)" ::: "memory");
  __builtin_amdgcn_s_barrier();

  const int NT = HI / 64;   // 64
  int cur = 0;
  for (int ti = 0; ti < NT - 1; ++ti) {
    F2_STAGE(cur ^ 1, (ti + 1) * 64)
    F2_COMPUTE(cur)
    asm volatile("s_waitcnt vmcnt(0)" ::: "memory");
    __builtin_amdgcn_s_barrier();
    cur ^= 1;
  }
  F2_COMPUTE(cur)

  #undef F2_STAGE
  #undef F2_COMPUTE

  float bias[4];
  #pragma unroll
  for (int ni = 0; ni < 4; ni++)
    bias[ni] = b2[e * DI + n0 + wn * 64 + ni * 16 + (lane & 15)];

  if (eo) {
    #pragma unroll
    for (int mi = 0; mi < 4; mi++) {
      #pragma unroll
      for (int rg = 0; rg < 4; rg++) {
        const int rowl = wm * 64 + mi * 16 + ((lane >> 4) << 2) + rg;
        const int gidx = mt * 256 + rowl;
        if (gidx < cnt) {
          float* erow = eo + (size_t)(hb + rowl) * DI;
          #pragma unroll
          for (int ni = 0; ni < 4; ni++) {
            const int col = n0 + wn * 64 + ni * 16 + (lane & 15);
            erow[col] = acc[mi][ni][rg] + bias[ni];
          }
        }
      }
    }
  } else {
    #pragma unroll
    for (int mi = 0; mi < 4; mi++) {
      #pragma unroll
      for (int rg = 0; rg < 4; rg++) {
        const int rowl = wm * 64 + mi * 16 + ((lane >> 4) << 2) + rg;
        const int gidx = mt * 256 + rowl;
        if (gidx < cnt) {
          const int tok = tok_list[eoff + gidx];
          const float gte = gate_list[eoff + gidx];
          float* orow = out + (size_t)tok * DI;
          #pragma unroll
          for (int ni = 0; ni < 4; ni++) {
            const int col = n0 + wn * 64 + ni * 16 + (lane & 15);
            atomicAdd(orow + col, (acc[mi][ni][rg] + bias[ni]) * gte);
          }
        }
      }
    }
  }
}

// ---------- kernel 7: out = x + g0*eo[p0] + g1*eo[p1] ----------
__global__ __launch_bounds__(256) void combine_k(
    const float* __restrict__ x, const float* __restrict__ eo,
    const int2* __restrict__ ipos, const float2* __restrict__ gates2,
    float* __restrict__ out)
{
  const int n = blockIdx.x, t = threadIdx.x;
  const int2 pp = ipos[n];
  const float2 gg = gates2[n];
  const float4 a = ((const float4*)(x  + (size_t)n    * DI))[t];
  const float4 b = ((const float4*)(eo + (size_t)pp.x * DI))[t];
  const float4 c = ((const float4*)(eo + (size_t)pp.y * DI))[t];
  float4 r;
  r.x = a.x + gg.x * b.x + gg.y * c.x;
  r.y = a.y + gg.x * b.y + gg.y * c.y;
  r.z = a.z + gg.x * b.z + gg.y * c.z;
  r.w = a.w + gg.x * b.w + gg.y * c.w;
  ((float4*)(out + (size_t)n * DI))[t] = r;
}

// ---------- launch ----------
extern "C" void kernel_launch(void* const* d_in, const int* in_sizes, int n_in,
                              void* d_out, int out_size, void* d_ws, size_t ws_size,
                              hipStream_t stream)
{
  const float* x   = (const float*)d_in[0];
  const float* gam = (const float*)d_in[1];
  const float* bet = (const float*)d_in[2];
  const float* gw  = (const float*)d_in[3];
  const float* w1  = (const float*)d_in[4];
  const float* b1  = (const float*)d_in[5];
  const float* w2  = (const float*)d_in[6];
  const float* b2  = (const float*)d_in[7];
  float* out = (float*)d_out;

  char* ws = (char*)d_ws;
  int*    counts = (int*)(ws + 0);
  int*    offs   = (int*)(ws + 64);
  int*    pairs  = (int*)(ws + 1024);
  float2* gates2 = (float2*)(ws + 20480);
  int*    tok    = (int*)(ws + 57344);
  float*  gate   = (float*)(ws + 90112);
  int2*   ipos   = (int2*)(ws + 122880);
  unsigned short* xnbf = (unsigned short*)(ws + 262656);
  unsigned short* wt   = (unsigned short*)(ws + 8651264);
  unsigned short* hbuf = (unsigned short*)(ws + 75760128);
  const bool use_eo = (ws_size >= 177472000ull);
  float* eo = use_eo ? (float*)(ws + 143917568) : (float*)nullptr;

  float* bal_out   = out + (size_t)NI * DI;
  float* probs_out = bal_out + 1;

  ln_router_k<<<NI / 4, 256, 0, stream>>>(x, gam, bet, gw, xnbf, probs_out, pairs, gates2);
  build_lists_k<<<1, 1024, 0, stream>>>(pairs, gates2, probs_out, counts, offs, tok, gate, ipos, bal_out);
  transpose_cvt_k<<<dim3(HI / 64, DI / 64, EI), 256, 0, stream>>>(w1, wt, DI, HI);
  if (!use_eo)
    copy_x_k<<<(NI * DI / 4) / 256, 256, 0, stream>>>(x, out);
  ffn1_k<<<dim3(HI / 256, 16, EI), 512, 0, stream>>>(xnbf, wt, b1, hbuf, tok, counts, offs);
  transpose_cvt_k<<<dim3(DI / 64, HI / 64, EI), 256, 0, stream>>>(w2, wt, HI, DI);
  ffn2_k<<<dim3(DI / 128, 16, EI), 512, 0, stream>>>(hbuf, wt, b2, out, tok, gate, counts, offs, eo);
  if (use_eo)
    combine_k<<<NI, 256, 0, stream>>>(x, eo, ipos, gates2, out);
}